// Round 15
// baseline (121.244 us; speedup 1.0000x reference)
//
#include <hip/hip_runtime.h>
#include <stdint.h>

// Swin shifted-window attention, MI355X (gfx950) — round 15.
// r14's LEAN MATH + r8's FULL-TLP GRID. Diagnosis: r12/r14's 4-wh-per-wave
// pipeline shrank the grid to 4096 waves (Occupancy 38%->19%, 1.5 waves/SIMD)
// while its register pipeline collapsed (VGPR=128) — a pure TLP loss that the
// ~35% lighter math happened to cancel. This round: ONE wh per wave (16384
// waves, 4096 blocks -> 16 queued blocks/CU), r14 math (1-MFMA S-tiles, f16
// bm, no hilo-K, O^T shuffle-free epilogue), r10's post-load sched_barrier.

constexpr int WSZ  = 7;
constexpr int NTOK = 49;
constexpr int NH_  = 16;
constexpr int HD_  = 32;
constexpr int SP   = 56;
constexpr int CH   = 512;
constexpr float LOG2E = 1.4426950408889634f;

typedef float    f32x4 __attribute__((ext_vector_type(4)));
typedef short    s16x8 __attribute__((ext_vector_type(8)));
typedef _Float16 f16x4 __attribute__((ext_vector_type(4)));

union FragU { uint32_t w[4]; s16x8 v; };

__device__ __forceinline__ uint32_t bf16_hibits(float x) {
    uint32_t u = __float_as_uint(x);
    u += 0x7fffu + ((u >> 16) & 1u);
    return u & 0xffff0000u;
}
__device__ __forceinline__ uint32_t pk_bf16(float a, float b) {
    return (bf16_hibits(a) >> 16) | bf16_hibits(b);
}

// ---------------- pre-kernel: bias+mask matrices (f16) ----------------
// bm[h*4+cls][q][m] (64x64 f16) = (bias+mask)*LOG2E; padding = -1000.
__global__ __launch_bounds__(256)
void build_bm(const float* __restrict__ bias, _Float16* __restrict__ bm)
{
    const int blk = blockIdx.x;          // h*4 + cls
    const int h = blk >> 2, cls = blk & 3;
    for (int idx = threadIdx.x; idx < 4096; idx += 256) {
        const int q = idx >> 6, m = idx & 63;
        float val;
        if (q >= NTOK || m >= NTOK) {
            val = -1000.0f;
        } else {
            const int iq = q / 7, jq = q % 7, im = m / 7, jm = m % 7;
            const int rpi = (iq - im + 6) * 13 + (jq - jm + 6);
            const float bv = bias[rpi * NH_ + h];
            const int rq = ((cls & 2) ? (iq < 4 ? 3 : 6) : 0)
                         + ((cls & 1) ? (jq < 4 ? 1 : 2) : 0);
            const int rm = ((cls & 2) ? (im < 4 ? 3 : 6) : 0)
                         + ((cls & 1) ? (jm < 4 ? 1 : 2) : 0);
            const float mask = (rq != rm) ? -100.0f : 0.0f;
            val = (bv + mask) * LOG2E;
        }
        bm[blk * 4096 + idx] = (_Float16)val;
    }
}

// ---------------- main MFMA kernel: one wh per wave ----------------
__global__ __launch_bounds__(256, 2)
void swin_mfma_kernel(const float* __restrict__ qg,
                      const float* __restrict__ kg,
                      const float* __restrict__ vg,
                      const _Float16* __restrict__ bm,
                      float* __restrict__ outg)
{
    const int wave = threadIdx.x >> 6;
    const int wh   = blockIdx.x * 4 + wave;
    const int h    = wh & (NH_ - 1);
    const int w    = wh >> 4;
    const int wc   = w & 7;
    const int wr   = (w >> 3) & 7;
    const int b    = w >> 6;

    const int lane = threadIdx.x & 63;
    const int g    = lane >> 4;
    const int l16  = lane & 15;

    // per-lane token offset (token = lane, clamped to 48)
    const int t  = lane < NTOK ? lane : NTOK - 1;
    const int it = t / 7, jt = t - 7 * it;
    int sr = wr * 7 + it + 3; if (sr >= SP) sr -= SP;
    int sc = wc * 7 + jt + 3; if (sc >= SP) sc -= SP;
    const int off_t = ((b * SP + sr) * SP + sc) * CH + h * HD_;

    // ---- all addresses ----
    int oQK[4];
#pragma unroll
    for (int tt = 0; tt < 4; ++tt) oQK[tt] = __shfl(off_t, 16 * tt + l16);
    int oV[16];
#pragma unroll
    for (int mc = 0; mc < 2; ++mc)
#pragma unroll
        for (int e = 0; e < 8; ++e) oV[8 * mc + e] = __shfl(off_t, 32 * mc + 8 * g + e);

    const int cls = ((wr == 7) ? 2 : 0) | ((wc == 7) ? 1 : 0);
    const _Float16* bmh = bm + ((size_t)h * 4 + cls) * 4096;

    // ---- issue all loads back-to-back (r10 lever) ----
    float4 qa[4][2], ka[4][2];
#pragma unroll
    for (int tt = 0; tt < 4; ++tt) {
        const float* qp = qg + oQK[tt] + 8 * g;
        const float* kp = kg + oQK[tt] + 8 * g;
        qa[tt][0] = *(const float4*)qp;  qa[tt][1] = *(const float4*)(qp + 4);
        ka[tt][0] = *(const float4*)kp;  ka[tt][1] = *(const float4*)(kp + 4);
    }
    float va[2][2][8];
#pragma unroll
    for (int mc = 0; mc < 2; ++mc)
#pragma unroll
        for (int dh = 0; dh < 2; ++dh)
#pragma unroll
            for (int e = 0; e < 8; ++e)
                va[mc][dh][e] = vg[oV[8 * mc + e] + 16 * dh + l16];
    f16x4 bmr[4][4];
#pragma unroll
    for (int tq = 0; tq < 4; ++tq)
#pragma unroll
        for (int tk = 0; tk < 4; ++tk)
            bmr[tq][tk] = *(const f16x4*)(bmh + (16 * tq + l16) * 64 + 16 * tk + 4 * g);

    // scheduling fence: loads cannot be sunk into consumers (r10: +5%)
    __builtin_amdgcn_sched_barrier(0);

    const float qs = 0.17677669529663687f * LOG2E;  // (1/sqrt(32))*log2(e)

    // ---- converts (Q pre-scaled bf16, K bf16, V bf16) ----
    s16x8 Qh[4], Kh[4], Vb[2][2];
#pragma unroll
    for (int tt = 0; tt < 4; ++tt) {
        FragU qh, kh;
        qh.w[0] = pk_bf16(qa[tt][0].x * qs, qa[tt][0].y * qs);
        qh.w[1] = pk_bf16(qa[tt][0].z * qs, qa[tt][0].w * qs);
        qh.w[2] = pk_bf16(qa[tt][1].x * qs, qa[tt][1].y * qs);
        qh.w[3] = pk_bf16(qa[tt][1].z * qs, qa[tt][1].w * qs);
        kh.w[0] = pk_bf16(ka[tt][0].x, ka[tt][0].y);
        kh.w[1] = pk_bf16(ka[tt][0].z, ka[tt][0].w);
        kh.w[2] = pk_bf16(ka[tt][1].x, ka[tt][1].y);
        kh.w[3] = pk_bf16(ka[tt][1].z, ka[tt][1].w);
        Qh[tt] = qh.v; Kh[tt] = kh.v;
    }
#pragma unroll
    for (int mc = 0; mc < 2; ++mc)
#pragma unroll
        for (int dh = 0; dh < 2; ++dh) {
            FragU fu;
#pragma unroll
            for (int wd = 0; wd < 4; ++wd)
                fu.w[wd] = pk_bf16(va[mc][dh][2 * wd], va[mc][dh][2 * wd + 1]);
            Vb[mc][dh] = fu.v;
        }

    // ---- S^T = K·Q^T tiles, fused exp2 + bf16 pack + denom ----
    uint32_t u0[4][4], u1[4][4];
    float inv[4];
#pragma unroll
    for (int tq = 0; tq < 4; ++tq) {
        float dsum = 0.f;
#pragma unroll
        for (int tk = 0; tk < 4; ++tk) {
            f32x4 a;
            a[0] = (float)bmr[tq][tk][0] - 23.f;
            a[1] = (float)bmr[tq][tk][1] - 23.f;
            a[2] = (float)bmr[tq][tk][2] - 23.f;
            a[3] = (float)bmr[tq][tk][3] - 23.f;
            a = __builtin_amdgcn_mfma_f32_16x16x32_bf16(Kh[tk], Qh[tq], a, 0, 0, 0);
            float e0 = __builtin_amdgcn_exp2f(a[0]);
            float e1 = __builtin_amdgcn_exp2f(a[1]);
            float e2 = __builtin_amdgcn_exp2f(a[2]);
            float e3 = __builtin_amdgcn_exp2f(a[3]);
            dsum += (e0 + e1) + (e2 + e3);
            u0[tq][tk] = pk_bf16(e0, e1);
            u1[tq][tk] = pk_bf16(e2, e3);
        }
        dsum += __shfl_xor(dsum, 16);
        dsum += __shfl_xor(dsum, 32);
        inv[tq] = 1.0f / (dsum + 1e-30f);   // lane-local for q = 16tq + l16
    }

    // ---- repack P (C-layout) -> fragments (r10-validated mapping) ----
    const int srcb = 32 * (g & 1) + l16;
    const bool hiG = (lane >= 32);
    s16x8 PA[4][2];
#pragma unroll
    for (int tq = 0; tq < 4; ++tq)
#pragma unroll
        for (int mc = 0; mc < 2; ++mc) {
            FragU fu;
#pragma unroll
            for (int wd = 0; wd < 4; ++wd) {
                const int sl = srcb + 16 * (wd >> 1);
                uint32_t A, B;
                if (wd & 1) {
                    A = __shfl(u1[tq][2 * mc],     sl);
                    B = __shfl(u1[tq][2 * mc + 1], sl);
                } else {
                    A = __shfl(u0[tq][2 * mc],     sl);
                    B = __shfl(u0[tq][2 * mc + 1], sl);
                }
                fu.w[wd] = hiG ? B : A;
            }
            PA[tq][mc] = fu.v;
        }

    // ---- O^T = V^T·P^T: mfma(A=Vb, B=PA) -> C[d][q] (r14-validated) ----
    // C-layout: col = l16 = q (tile tq), row = 4g+r = d (within 16dh).
    // Store: lane-local float4 at oQK[tq] + 16dh + 4g; iv lane-local.
#pragma unroll
    for (int tq = 0; tq < 4; ++tq) {
        const float iv = inv[tq];
        const bool ok = (tq < 3) || (l16 == 0);     // token 16tq+l16 < 49
#pragma unroll
        for (int dh = 0; dh < 2; ++dh) {
            f32x4 a = {0.f, 0.f, 0.f, 0.f};
            a = __builtin_amdgcn_mfma_f32_16x16x32_bf16(Vb[0][dh], PA[tq][0], a, 0, 0, 0);
            a = __builtin_amdgcn_mfma_f32_16x16x32_bf16(Vb[1][dh], PA[tq][1], a, 0, 0, 0);
            if (ok) {
                float4 st;
                st.x = a[0] * iv; st.y = a[1] * iv;
                st.z = a[2] * iv; st.w = a[3] * iv;
                *(float4*)(outg + oQK[tq] + 16 * dh + 4 * g) = st;
            }
        }
    }
}

// ---------------- fallback scalar kernel (round-3) ----------------
__global__ __launch_bounds__(256)
void swin_block_scalar(const float* __restrict__ qg,
                       const float* __restrict__ kg,
                       const float* __restrict__ vg,
                       const float* __restrict__ bias,
                       float* __restrict__ outg)
{
    const int wave = __builtin_amdgcn_readfirstlane(threadIdx.x >> 6);
    const int wh   = blockIdx.x * 4 + wave;
    const int h    = wh & (NH_ - 1);
    const int w    = wh >> 4;
    const int wc   = w & 7;
    const int wr   = (w >> 3) & 7;
    const int b    = w >> 6;

    const int lane = threadIdx.x & 63;
    const int rr   = lane < NTOK ? lane : NTOK - 1;
    const int i    = rr / WSZ;
    const int j    = rr - i * WSZ;

    const int hp = wr * WSZ + i;
    const int wp = wc * WSZ + j;
    int sr = hp + 3; if (sr >= SP) sr -= SP;
    int sc = wp + 3; if (sc >= SP) sc -= SP;
    const int rowoff = ((b * SP + sr) * SP + sc) * CH + h * HD_;
    const int reg_r = (hp < 49 ? 0 : (hp < 53 ? 3 : 6))
                    + (wp < 49 ? 0 : (wp < 53 ? 1 : 2));
    const float qscale = 0.17677669529663687f * LOG2E;

    float qr[HD_];
    {
        const float4* qp = reinterpret_cast<const float4*>(qg + rowoff);
#pragma unroll
        for (int tt = 0; tt < HD_ / 4; ++tt) {
            float4 x = qp[tt];
            qr[4*tt+0] = x.x * qscale; qr[4*tt+1] = x.y * qscale;
            qr[4*tt+2] = x.z * qscale; qr[4*tt+3] = x.w * qscale;
        }
    }
    const int biaslane = (i * 13 + j) * 16 + h;
    float o[HD_];
#pragma unroll
    for (int d = 0; d < HD_; ++d) o[d] = 0.f;
    float denom = 0.f;
    const float* kb = kg + b * SP * SP * CH + h * HD_;
    const float* vb = vg + b * SP * SP * CH + h * HD_;

    for (int ic = 0; ic < WSZ; ++ic) {
        const int hpc = wr * WSZ + ic;
        int src_r = hpc + 3; if (src_r >= SP) src_r -= SP;
        const int regh_c = (hpc < 49 ? 0 : (hpc < 53 ? 3 : 6));
        const float* krow0 = kb + src_r * SP * CH;
        const float* vrow0 = vb + src_r * SP * CH;
        float e[WSZ];
#pragma unroll
        for (int u = 0; u < WSZ; ++u) {
            const int wpc = wc * WSZ + u;
            int src_c = wpc + 3; if (src_c >= SP) src_c -= SP;
            const int reg_c = regh_c + (wpc < 49 ? 0 : (wpc < 53 ? 1 : 2));
            const float* krow = krow0 + src_c * CH;
            const float bv = bias[biaslane + ((6 - ic) * 13 + (6 - u)) * 16];
            float s0 = fmaf(bv, LOG2E, (reg_r != reg_c) ? -167.26950408889634f : -23.0f);
            float s1 = 0.f, s2 = 0.f, s3 = 0.f;
#pragma unroll
            for (int d = 0; d < HD_; d += 4) {
                s0 = fmaf(qr[d+0], krow[d+0], s0);
                s1 = fmaf(qr[d+1], krow[d+1], s1);
                s2 = fmaf(qr[d+2], krow[d+2], s2);
                s3 = fmaf(qr[d+3], krow[d+3], s3);
            }
            e[u] = exp2f((s0 + s1) + (s2 + s3));
            denom += e[u];
        }
#pragma unroll
        for (int u = 0; u < WSZ; ++u) {
            const int wpc = wc * WSZ + u;
            int src_c = wpc + 3; if (src_c >= SP) src_c -= SP;
            const float* vrow = vrow0 + src_c * CH;
            const float ev = e[u];
#pragma unroll
            for (int d = 0; d < HD_; ++d) o[d] = fmaf(ev, vrow[d], o[d]);
        }
    }
    const float invd = 1.0f / denom;
    if (lane < NTOK) {
        float4* op = reinterpret_cast<float4*>(outg + rowoff);
#pragma unroll
        for (int tt = 0; tt < HD_ / 4; ++tt) {
            float4 x;
            x.x = o[4*tt+0] * invd; x.y = o[4*tt+1] * invd;
            x.z = o[4*tt+2] * invd; x.w = o[4*tt+3] * invd;
            op[tt] = x;
        }
    }
}

extern "C" void kernel_launch(void* const* d_in, const int* in_sizes, int n_in,
                              void* d_out, int out_size, void* d_ws, size_t ws_size,
                              hipStream_t stream) {
    const float* q    = (const float*)d_in[0];
    const float* k    = (const float*)d_in[1];
    const float* v    = (const float*)d_in[2];
    const float* bias = (const float*)d_in[3];
    float* out        = (float*)d_out;

    const int B   = in_sizes[0] / (SP * SP * CH);
    const int nwh = B * (SP / WSZ) * (SP / WSZ) * NH_;   // 16384

    const size_t bm_bytes = (size_t)NH_ * 4 * 4096 * sizeof(_Float16);  // 512 KB
    if (ws_size >= bm_bytes) {
        _Float16* bm = (_Float16*)d_ws;
        hipLaunchKernelGGL(build_bm, dim3(NH_ * 4), dim3(256), 0, stream, bias, bm);
        // one wh per wave, 4 waves per block -> nwh/4 = 4096 blocks
        hipLaunchKernelGGL(swin_mfma_kernel, dim3(nwh / 4), dim3(256), 0, stream,
                           q, k, v, bm, out);
    } else {
        hipLaunchKernelGGL(swin_block_scalar, dim3(nwh / 4), dim3(256), 0, stream,
                           q, k, v, bias, out);
    }
}